// Round 4
// baseline (2723.197 us; speedup 1.0000x reference)
//
#include <hip/hip_runtime.h>
#include <hip/hip_bf16.h>

#define T_ 2048
#define B_ 1024
#define H_ 256
#define I_ 8
#define A_ 8
#define DT_ 0.1f
#define EPS_ 1e-5f
#define LSTR 304   // shorts per h row (pad: 152 dwords)
#define CH 32      // x-staging chunk (timesteps)
#define RBT 4      // total batch rows per block = 2 groups x 2 rows
#define REDW 10    // float2 per redt row (8 wave partials + pad)

typedef __attribute__((ext_vector_type(8))) short bf16x8;
typedef __attribute__((ext_vector_type(4))) float f32x4;

#if __has_builtin(__builtin_amdgcn_cvt_pk_bf16_f32)
typedef __attribute__((ext_vector_type(2))) __bf16 bf16x2;
__device__ __forceinline__ int pk2bf(float a, float b) {
    bf16x2 r = __builtin_amdgcn_cvt_pk_bf16_f32(a, b);
    return __builtin_bit_cast(int, r);
}
#else
__device__ __forceinline__ short f2bf1(float f) {
    unsigned u = __builtin_bit_cast(unsigned, f);
    u += 0x7fffu + ((u >> 16) & 1u);   // RNE
    return (short)(u >> 16);
}
__device__ __forceinline__ int pk2bf(float a, float b) {
    return (int)(unsigned short)f2bf1(a) | ((int)f2bf1(b) << 16);
}
#endif

__device__ __forceinline__ void gemm_step(const bf16x8 (&af)[2][9],
                                          const short* hrow, const short* xb,
                                          const f32x4& pb0, const f32x4& pb1,
                                          f32x4& o0, f32x4& o1) {
    const f32x4 z = {0.f, 0.f, 0.f, 0.f};
    f32x4 c0a = pb0, c1a = pb1, c0b = z, c1b = z;
#pragma unroll
    for (int ks = 0; ks < 4; ++ks) {
        bf16x8 bA = *reinterpret_cast<const bf16x8*>(hrow + ks * 32);
        bf16x8 bB = *reinterpret_cast<const bf16x8*>(hrow + (ks + 4) * 32);
        c0a = __builtin_amdgcn_mfma_f32_16x16x32_bf16(af[0][ks],     bA, c0a, 0, 0, 0);
        c1a = __builtin_amdgcn_mfma_f32_16x16x32_bf16(af[1][ks],     bA, c1a, 0, 0, 0);
        c0b = __builtin_amdgcn_mfma_f32_16x16x32_bf16(af[0][ks + 4], bB, c0b, 0, 0, 0);
        c1b = __builtin_amdgcn_mfma_f32_16x16x32_bf16(af[1][ks + 4], bB, c1b, 0, 0, 0);
    }
    bf16x8 b8 = *reinterpret_cast<const bf16x8*>(xb);
    c0a = __builtin_amdgcn_mfma_f32_16x16x32_bf16(af[0][8], b8, c0a, 0, 0, 0);
    c1a = __builtin_amdgcn_mfma_f32_16x16x32_bf16(af[1][8], b8, c1a, 0, 0, 0);
    o0 = c0a + c0b;
    o1 = c1a + c1b;
}

// in-lane fold over this lane's 8 cols + 2 shfl hops (fold quads) -> wave partial;
// lanes 0,1 (rows 0,1) store (S,SQ) for this wave.  [verified round-0/1 reduction]
__device__ __forceinline__ void fold_write(const f32x4& a0, const f32x4& a1,
                                           float2* dst, bool wr) {
    float S  = ((a0[0] + a0[1]) + (a0[2] + a0[3])) + ((a1[0] + a1[1]) + (a1[2] + a1[3]));
    float SQ = fmaf(a0[0], a0[0], fmaf(a0[1], a0[1], fmaf(a0[2], a0[2], a0[3] * a0[3])))
             + fmaf(a1[0], a1[0], fmaf(a1[1], a1[1], fmaf(a1[2], a1[2], a1[3] * a1[3])));
    S += __shfl_xor(S, 16, 64);  SQ += __shfl_xor(SQ, 16, 64);
    S += __shfl_xor(S, 32, 64);  SQ += __shfl_xor(SQ, 32, 64);
    if (wr) *dst = make_float2(S, SQ);
}

// sum 8 wave partials (4x ds_read_b128, broadcast) -> mu, rstd
__device__ __forceinline__ void ln_stats(const float4* rr, float& mu, float& rstd) {
    float4 q0 = rr[0], q1 = rr[1], q2 = rr[2], q3 = rr[3];
    float St  = ((q0.x + q0.z) + (q1.x + q1.z)) + ((q2.x + q2.z) + (q3.x + q3.z));
    float SQt = ((q0.y + q0.w) + (q1.y + q1.w)) + ((q2.y + q2.w) + (q3.y + q3.w));
    mu = St * (1.f / 256.f);
    float var = fmaf(SQt, 1.f / 256.f, -mu * mu);
    rstd = __builtin_amdgcn_rsqf(var + EPS_);
}

__device__ __forceinline__ float tail_upd(const f32x4& a0, const f32x4& a1,
                                          int mtj, int ri, float mu, float rstd,
                                          float pg, float pb, float pd, float hprev) {
    float v0 = mtj ? a1[0] : a0[0];
    float v1 = mtj ? a1[1] : a0[1];
    float v2 = mtj ? a1[2] : a0[2];
    float v3 = mtj ? a1[3] : a0[3];
    float va = (ri & 1) ? v1 : v0;
    float vb = (ri & 1) ? v3 : v2;
    float v  = (ri & 2) ? vb : va;
    float tt = fmaf(v, rstd, -mu * rstd);
    float z2 = fmaf(tt, pg, pb);                 // 2z/ln2
    float e  = __builtin_amdgcn_exp2f(z2);       // e^(2z)
    float rc = __builtin_amdgcn_rcpf(e + 1.f);
    float fd = fmaf(rc, -2.f * DT_, DT_);        // DT*tanh(z)
    float h  = fmaf(hprev, pd, fd);
    return __builtin_amdgcn_fmed3f(h, -10.f, 10.f);
}

__launch_bounds__(512, 2)
__global__ void liquid_kernel(const float* __restrict__ x,
                              const float* __restrict__ W_in,
                              const float* __restrict__ b_in,
                              const float* __restrict__ tau_param,
                              const float* __restrict__ W_rec,
                              const float* __restrict__ g1,
                              const float* __restrict__ beta1,
                              const float* __restrict__ g2,
                              const float* __restrict__ beta2,
                              const float* __restrict__ head_w,
                              const float* __restrict__ head_b,
                              float* __restrict__ out) {
    __shared__ short  h_ldsA[2 * LSTR];          // group A h (rows 0,1)
    __shared__ short  h_ldsB[2 * LSTR];          // group B h (rows 2,3)
    __shared__ short  xstage[2][CH][RBT][8];     // x chunks (bf16), rows 0..3
    __shared__ alignas(16) int zero16[4];
    __shared__ alignas(16) float2 redtA[2][REDW];
    __shared__ alignas(16) float2 redtB[2][REDW];
    __shared__ float  hw[H_ * A_];
    __shared__ float  outp[8][RBT][A_];

    const int tid  = threadIdx.x;
    const int w    = tid >> 6;
    const int lane = tid & 63;
    const int quad = lane >> 4;
    const int l15  = lane & 15;
    const int row  = l15 & 1;      // local row within group (8 aliases)
    const int cj   = l15 >> 1;
    const int mtj  = cj >> 2;
    const int ri   = cj & 3;
    const int r0   = blockIdx.x * RBT;

    for (int i = tid; i < 2 * LSTR; i += 512) { h_ldsA[i] = 0; h_ldsB[i] = 0; }
    if (tid < 4) zero16[tid] = 0;

    // ---- per-lane params (shared by both groups: same col assignment) ----
    f32x4 pbin0, pbin1;
    float p_g1, p_b1, p_decay;
#pragma unroll
    for (int r = 0; r < 4; ++r) {
        pbin0[r] = b_in[w * 32 + quad * 4 + r];
        pbin1[r] = b_in[w * 32 + 16 + quad * 4 + r];
    }
    {
        int c = w * 32 + mtj * 16 + quad * 4 + ri;
        p_g1 = g1[c] * 2.885390082f;
        p_b1 = beta1[c] * 2.885390082f;
        float tp = tau_param[c];
        float sp = (tp > 20.f) ? tp : log1pf(expf(tp));
        p_decay = 1.0f - DT_ / sp;
    }

    // ---- A fragments resident in regs (shared by both groups) ----
    bf16x8 afrag[2][9];
#pragma unroll
    for (int mt = 0; mt < 2; ++mt) {
        int cA = w * 32 + mt * 16 + l15;
#pragma unroll
        for (int ks = 0; ks < 9; ++ks) {
            bf16x8 f;
#pragma unroll
            for (int j = 0; j < 8; ++j) {
                int kg = ks * 32 + quad * 8 + j;
                float v;
                if (kg < 256)      v = W_rec[kg * H_ + cA];
                else if (kg < 264) v = W_in[(kg - 256) * H_ + cA];
                else               v = 0.f;
                f[j] = (short)pk2bf(v, v);
            }
            afrag[mt][ks] = f;
        }
    }

    // ---- x chunk loader: threads 0..255, rows 0..3 ----
    const int xrow = (tid >> 6) & 3, xf4 = tid & 63;
    const int xt = xf4 >> 1, xi0 = (xf4 & 1) * 4;
    const bool xldr = (tid < 256);
    const float* xrbase = x + (size_t)(r0 + xrow) * T_ * I_;
    float4 xr;

    if (xldr) {
        xr = ((const float4*)xrbase)[xf4];                       // chunk 0
        int2 pk = make_int2(pk2bf(xr.x, xr.y), pk2bf(xr.z, xr.w));
        *reinterpret_cast<int2*>(&xstage[0][xt][xrow][xi0]) = pk;
        xr = ((const float4*)(xrbase + (size_t)CH * I_))[xf4];   // chunk 1
    }

    float hregA = 0.f, hregB = 0.f;

    const short* hrowA = &h_ldsA[row * LSTR + quad * 8];
    const short* hrowB = &h_ldsB[row * LSTR + quad * 8];
    short* hwrA = &h_ldsA[row * LSTR + w * 32 + mtj * 16 + quad * 4 + ri];
    short* hwrB = &h_ldsB[row * LSTR + w * 32 + mtj * 16 + quad * 4 + ri];
    float2* redwA = &redtA[row][w];
    float2* redwB = &redtB[row][w];
    const float4* rrA = reinterpret_cast<const float4*>(&redtA[row][0]);
    const float4* rrB = reinterpret_cast<const float4*>(&redtB[row][0]);
    const bool wrt = (lane < 2);

    __syncthreads();   // h zeros + chunk0 visible

    f32x4 aA0, aA1, aB0, aB1;

    // ---- prologue: GEMM_A(0) ----
    {
        const short* xbA = (quad == 0) ? &xstage[0][0][row][0] : (const short*)zero16;
        gemm_step(afrag, hrowA, xbA, pbin0, pbin1, aA0, aA1);
        fold_write(aA0, aA1, redwA, wrt);
    }
    __syncthreads();   // redtA(0) ready

    // ---- main loop: skewed two-group pipeline ----
    for (int t = 0; t < T_ - 1; ++t) {
        const int tc  = t & (CH - 1);
        const int c   = t >> 5;
        const int buf = c & 1;

        if (xldr && tc == 16) {   // convert held regs (chunk c+1) into idle buffer
            int2 pk = make_int2(pk2bf(xr.x, xr.y), pk2bf(xr.z, xr.w));
            *reinterpret_cast<int2*>(&xstage[buf ^ 1][xt][xrow][xi0]) = pk;
        }
        if (xldr && tc == 18) {   // issue loads for chunk c+2
            int cc = c + 2; if (cc > (T_ / CH) - 1) cc = (T_ / CH) - 1;
            xr = ((const float4*)(xrbase + (size_t)cc * CH * I_))[xf4];
        }

        // ---- first half: GEMM_B(t) [MFMA]  ||  finish A(t) [VALU] ----
        {
            const short* xbB = (quad == 0) ? &xstage[buf][tc][2 + row][0] : (const short*)zero16;
            gemm_step(afrag, hrowB, xbB, pbin0, pbin1, aB0, aB1);
            float mu, rstd;
            ln_stats(rrA, mu, rstd);
            hregA = tail_upd(aA0, aA1, mtj, ri, mu, rstd, p_g1, p_b1, p_decay, hregA);
            *hwrA = (short)pk2bf(hregA, hregA);     // h_A(t+1)
            fold_write(aB0, aB1, redwB, wrt);
        }
        __syncthreads();   // h_A(t+1) + redtB(t) ready

        // ---- second half: GEMM_A(t+1) [MFMA]  ||  finish B(t) [VALU] ----
        {
            const int t1 = t + 1, tc1 = t1 & (CH - 1), buf1 = (t1 >> 5) & 1;
            const short* xbA = (quad == 0) ? &xstage[buf1][tc1][row][0] : (const short*)zero16;
            gemm_step(afrag, hrowA, xbA, pbin0, pbin1, aA0, aA1);
            float mu, rstd;
            ln_stats(rrB, mu, rstd);
            hregB = tail_upd(aB0, aB1, mtj, ri, mu, rstd, p_g1, p_b1, p_decay, hregB);
            *hwrB = (short)pk2bf(hregB, hregB);     // h_B(t+1)
            fold_write(aA0, aA1, redwA, wrt);
        }
        __syncthreads();   // h_B(t+1) + redtA(t+1) ready
    }

    // ---- final step t = T-1 ----
    {
        const int t = T_ - 1, tc = t & (CH - 1), buf = (t >> 5) & 1;
        const short* xbB = (quad == 0) ? &xstage[buf][tc][2 + row][0] : (const short*)zero16;
        gemm_step(afrag, hrowB, xbB, pbin0, pbin1, aB0, aB1);
        float mu, rstd;
        ln_stats(rrA, mu, rstd);
        hregA = tail_upd(aA0, aA1, mtj, ri, mu, rstd, p_g1, p_b1, p_decay, hregA);  // final h_A
        fold_write(aB0, aB1, redwB, wrt);
        __syncthreads();
        ln_stats(rrB, mu, rstd);
        hregB = tail_upd(aB0, aB1, mtj, ri, mu, rstd, p_g1, p_b1, p_decay, hregB);  // final h_B
    }

    // ---- epilogue: out = LN(h_T; g2,b2) @ head_w + head_b, per group ----
    for (int i = tid; i < H_ * A_; i += 512) hw[i] = head_w[i];

    float hr[2] = {hregA, hregB};
#pragma unroll
    for (int g = 0; g < 2; ++g) {
        __syncthreads();   // hw ready (g=0) / redtA reads of prev g done (g=1)
        float S2 = hr[g], SQ2 = hr[g] * hr[g];
        S2 += __shfl_xor(S2, 2, 64);   SQ2 += __shfl_xor(SQ2, 2, 64);
        S2 += __shfl_xor(S2, 4, 64);   SQ2 += __shfl_xor(SQ2, 4, 64);
        S2 += __shfl_xor(S2, 8, 64);   SQ2 += __shfl_xor(SQ2, 8, 64);
        S2 += __shfl_xor(S2, 16, 64);  SQ2 += __shfl_xor(SQ2, 16, 64);
        S2 += __shfl_xor(S2, 32, 64);  SQ2 += __shfl_xor(SQ2, 32, 64);
        if (lane < 2) redtA[row][w] = make_float2(S2, SQ2);
        __syncthreads();
        const float4* rr = reinterpret_cast<const float4*>(&redtA[row][0]);
        float4 q0 = rr[0], q1 = rr[1], q2 = rr[2], q3 = rr[3];
        float St  = ((q0.x + q0.z) + (q1.x + q1.z)) + ((q2.x + q2.z) + (q3.x + q3.z));
        float SQt = ((q0.y + q0.w) + (q1.y + q1.w)) + ((q2.y + q2.w) + (q3.y + q3.w));
        float mu   = St * (1.f / 256.f);
        float var  = fmaf(SQt, 1.f / 256.f, -mu * mu);
        float rstd = __builtin_amdgcn_rsqf(var + EPS_);

        int cc = w * 32 + mtj * 16 + quad * 4 + ri;
        float lnh = (hr[g] - mu) * rstd * g2[cc] + beta2[cc];
        float4 w0 = *reinterpret_cast<const float4*>(&hw[cc * 8]);
        float4 w1 = *reinterpret_cast<const float4*>(&hw[cc * 8 + 4]);
        float pa[8] = {lnh * w0.x, lnh * w0.y, lnh * w0.z, lnh * w0.w,
                       lnh * w1.x, lnh * w1.y, lnh * w1.z, lnh * w1.w};
#pragma unroll
        for (int a = 0; a < 8; ++a) {
            pa[a] += __shfl_xor(pa[a], 2, 64);
            pa[a] += __shfl_xor(pa[a], 4, 64);
            pa[a] += __shfl_xor(pa[a], 8, 64);
            pa[a] += __shfl_xor(pa[a], 16, 64);
            pa[a] += __shfl_xor(pa[a], 32, 64);
        }
        if (lane < 2) {
#pragma unroll
            for (int a = 0; a < 8; ++a) outp[w][g * 2 + row][a] = pa[a];
        }
    }
    __syncthreads();
    if (tid < RBT * A_) {
        int r = tid >> 3, a = tid & 7;
        float s = head_b[a];
#pragma unroll
        for (int ww = 0; ww < 8; ++ww) s += outp[ww][r][a];
        out[(size_t)(r0 + r) * A_ + a] = s;
    }
}

extern "C" void kernel_launch(void* const* d_in, const int* in_sizes, int n_in,
                              void* d_out, int out_size, void* d_ws, size_t ws_size,
                              hipStream_t stream) {
    const float* x         = (const float*)d_in[0];
    const float* W_in      = (const float*)d_in[1];
    const float* b_in      = (const float*)d_in[2];
    const float* tau_param = (const float*)d_in[3];
    const float* W_rec     = (const float*)d_in[4];
    const float* g1        = (const float*)d_in[5];
    const float* beta1     = (const float*)d_in[6];
    const float* g2        = (const float*)d_in[7];
    const float* beta2     = (const float*)d_in[8];
    const float* head_w    = (const float*)d_in[9];
    const float* head_b    = (const float*)d_in[10];
    float* out = (float*)d_out;

    liquid_kernel<<<B_ / RBT, 512, 0, stream>>>(x, W_in, b_in, tau_param, W_rec,
                                                g1, beta1, g2, beta2, head_w, head_b, out);
}